// Round 6
// baseline (354.883 us; speedup 1.0000x reference)
//
#include <hip/hip_runtime.h>
#include <hip/hip_bf16.h>

#define S 9216      // 96*96 spatial positions
#define C 256       // channels
#define NCT 12      // 256-col tiles per GEMM block
#define NG  (NCT*8) // kt-steps per block (96)
#define SCH 1152    // s-chunk for rowsum/colmax kernels

typedef __bf16 bf16x8 __attribute__((ext_vector_type(8)));
typedef float f32x4 __attribute__((ext_vector_type(4)));
typedef unsigned short us8 __attribute__((ext_vector_type(8)));
typedef unsigned short us4 __attribute__((ext_vector_type(4)));

#define GLOAD_LDS16(g, l) __builtin_amdgcn_global_load_lds( \
    (const __attribute__((address_space(1))) void*)(g),     \
    (__attribute__((address_space(3))) void*)(l), 16, 0, 0)

#define A2C 2.8853900817779268f   // 2*log2(e) = 2/ln2

__device__ __forceinline__ float bf2f(unsigned short u) {
    return __uint_as_float(((unsigned)u) << 16);
}
__device__ __forceinline__ unsigned short f2bfbits(float x) {
    __hip_bfloat16 h = __float2bfloat16(x);
    return *reinterpret_cast<unsigned short*>(&h);
}

// ---------------- mean of gt over spatial, per channel ----------------
__global__ __launch_bounds__(256) void k_mean(const float* __restrict__ gt,
                                              float* __restrict__ meanT) {
    const int c = blockIdx.x;
    const float* p = gt + (size_t)c * S;
    float s = 0.f;
    for (int i = threadIdx.x; i < S; i += 256) s += p[i];
    for (int m = 1; m < 64; m <<= 1) s += __shfl_xor(s, m, 64);
    __shared__ float red[4];
    if ((threadIdx.x & 63) == 0) red[threadIdx.x >> 6] = s;
    __syncthreads();
    if (threadIdx.x == 0)
        meanT[c] = (red[0] + red[1] + red[2] + red[3]) * (1.0f / S);
}

// ---------------- partial centered sum-of-squares over 32-channel parts ----
// grid 288 = 8 parts x 36 s-blocks; fully coalesced 256B reads; no atomics.
__global__ __launch_bounds__(256) void k_ssq(const float* __restrict__ img,
                                             const float* __restrict__ gt,
                                             const float* __restrict__ meanT,
                                             float* __restrict__ ssqP) {  // [16][S]
    __shared__ float sm[32];
    const int part = blockIdx.x & 7;
    const int sb   = blockIdx.x >> 3;
    const int t    = threadIdx.x;
    if (t < 32) sm[t] = meanT[part * 32 + t];
    __syncthreads();
    const int s = sb * 256 + t;
    float si = 0.f, st = 0.f;
    #pragma unroll 8
    for (int k = 0; k < 32; ++k) {
        const int c = part * 32 + k;
        const float m  = sm[k];
        const float di = img[(size_t)c * S + s] - m;
        const float dt = gt [(size_t)c * S + s] - m;
        si += di * di;
        st += dt * dt;
    }
    ssqP[(size_t)part * S + s]       = si;
    ssqP[(size_t)(part + 8) * S + s] = st;
}

// ---------------- write normalized bf16 A,B (transposed to [S][C]) --------
__global__ __launch_bounds__(256) void k_write(const float* __restrict__ img,
                                               const float* __restrict__ gt,
                                               const float* __restrict__ meanT,
                                               const float* __restrict__ ssqP,
                                               __hip_bfloat16* __restrict__ A,
                                               __hip_bfloat16* __restrict__ B) {
    __shared__ float sm[32];
    const int part = blockIdx.x & 7;
    const int sb   = blockIdx.x >> 3;
    const int t    = threadIdx.x;
    if (t < 32) sm[t] = meanT[part * 32 + t];
    __syncthreads();
    const int s = sb * 256 + t;
    float si = 0.f, st = 0.f;
    #pragma unroll
    for (int p = 0; p < 8; ++p) {
        si += ssqP[(size_t)p * S + s];
        st += ssqP[(size_t)(p + 8) * S + s];
    }
    const float ri = 1.0f / fmaxf(sqrtf(si), 1e-12f);
    const float rt = 1.0f / fmaxf(sqrtf(st), 1e-12f);
    const int c0 = part * 32;
    #pragma unroll
    for (int cc = 0; cc < 4; ++cc) {
        us8 va, vb;
        #pragma unroll
        for (int e = 0; e < 8; ++e) {
            const int c = c0 + cc * 8 + e;
            const float m = sm[cc * 8 + e];
            va[e] = f2bfbits((img[(size_t)c * S + s] - m) * ri);
            vb[e] = f2bfbits((gt [(size_t)c * S + s] - m) * rt);
        }
        *reinterpret_cast<us8*>(A + (size_t)s * C + c0 + cc * 8) = va;
        *reinterpret_cast<us8*>(B + (size_t)s * C + c0 + cc * 8) = vb;
    }
}

// ---------------- init reduction buffers ----------------
__global__ __launch_bounds__(256) void k_init(float* __restrict__ rowmin,
                                              float* __restrict__ rowsum,
                                              float* __restrict__ colmaxLog) {
    const int i = blockIdx.x * 256 + threadIdx.x;
    if (i < S) {
        rowmin[i]     = __uint_as_float(0x7f800000u);  // +inf
        rowsum[i]     = 0.f;
        colmaxLog[i]  = 0.f;   // biased log2 max; 0 == 2^-64 ~ 0
    }
}

// ---------------- GEMM pass: store raw^T + rowmin ----------------
// 64-row A panel (full K=256 resident, 32KB) + 256-col B stages (2x16KB).
// LDS = 64KB -> TRUE 2 blocks/CU (r4/r5 were silently 1 block/CU at 80KB).
// Wave tile 64x64 (m97 ratio). Double-buffered B, counted vmcnt(4).
__global__ __launch_bounds__(256, 2) void k_gemm_store(const __hip_bfloat16* __restrict__ A,
                                                       const __hip_bfloat16* __restrict__ B,
                                                       float* __restrict__ rowmin,
                                                       __hip_bfloat16* __restrict__ Q) {
    __shared__ alignas(16) __hip_bfloat16 As[64 * 256];       // 32 KB
    __shared__ alignas(16) __hip_bfloat16 Bs[2 * 256 * 32];   // 32 KB
    const int tid  = threadIdx.x;
    const int lane = tid & 63;
    const int wid  = tid >> 6;       // wave owns 64-col strip wid*64
    // XCD-aware bijective swizzle: 432 = 8 * 54
    const int orig = blockIdx.x;
    const int wg   = (orig & 7) * 54 + (orig >> 3);
    const int rowBase = (wg / 3) * 64;
    const int cb0     = (wg % 3) * 3072;

    const int frow = lane & 15;
    const int kgrp = lane >> 4;

    // ---- stage A (full K, 8 loads/thread)
    {
        const int arow_lo = lane >> 5;
        const int achunk  = lane & 31;
        #pragma unroll
        for (int j = 0; j < 8; ++j) {
            const int row = wid * 16 + j * 2 + arow_lo;
            const int cc  = achunk ^ (row & 7);
            GLOAD_LDS16(A + (size_t)(rowBase + row) * C + cc * 8,
                        &As[(wid * 16 + j * 2) * 256 + lane * 8]);
        }
    }
    // ---- B prologue: stages g=0,1 (4 loads/thread each)
    const int bcol_lo = lane >> 2;
    const int bchunk  = (lane & 3) ^ ((lane >> 3) & 3);
    #pragma unroll
    for (int g = 0; g < 2; ++g) {
        const int cb = cb0 + (g >> 3) * 256;
        const int kt = g & 7;
        #pragma unroll
        for (int i = 0; i < 4; ++i) {
            const int col = wid * 16 + i * 64 + bcol_lo;
            GLOAD_LDS16(B + (size_t)(cb + col) * C + kt * 32 + bchunk * 8,
                        &Bs[(g & 1) * 8192 + wid * 512 + i * 2048 + lane * 8]);
        }
    }

    const int bswz = (kgrp ^ ((frow >> 1) & 3)) * 8;

    for (int t = 0; t < NCT; ++t) {
        f32x4 acc[4][4] = {};
        #pragma unroll
        for (int kt = 0; kt < 8; ++kt) {
            const int g = t * 8 + kt;
            if (g < NG - 1) asm volatile("s_waitcnt vmcnt(4)" ::: "memory");
            else            asm volatile("s_waitcnt vmcnt(0)" ::: "memory");
            __builtin_amdgcn_s_barrier();

            bf16x8 af[4], bfr[4];
            #pragma unroll
            for (int m = 0; m < 4; ++m) {
                const int row = m * 16 + frow;
                const int p   = (kt * 4 + kgrp) ^ (frow & 7);
                af[m] = *reinterpret_cast<const bf16x8*>(&As[row * 256 + p * 8]);
            }
            const int bbase = (g & 1) * 8192;
            #pragma unroll
            for (int n = 0; n < 4; ++n) {
                const int col = wid * 64 + n * 16 + frow;
                bfr[n] = *reinterpret_cast<const bf16x8*>(&Bs[bbase + col * 32 + bswz]);
            }
            #pragma unroll
            for (int m = 0; m < 4; ++m)
                #pragma unroll
                for (int n = 0; n < 4; ++n)
                    acc[m][n] = __builtin_amdgcn_mfma_f32_16x16x32_bf16(af[m], bfr[n], acc[m][n], 0, 0, 0);

            __builtin_amdgcn_s_barrier();

            if (g + 2 < NG) {
                const int g2 = g + 2;
                const int cb = cb0 + (g2 >> 3) * 256;
                const int k2 = g2 & 7;
                #pragma unroll
                for (int i = 0; i < 4; ++i) {
                    const int col = wid * 16 + i * 64 + bcol_lo;
                    GLOAD_LDS16(B + (size_t)(cb + col) * C + k2 * 32 + bchunk * 8,
                                &Bs[(g2 & 1) * 8192 + wid * 512 + i * 2048 + lane * 8]);
                }
            }
        }

        // ---- epilogue tile t (overlaps next tile's 2 in-flight B stages)
        // C/D map: r_local = m*16 + kgrp*4 + q, c = wid*64 + n*16 + frow
        const int colBase = cb0 + t * 256;
        float vmin[4][4];
        #pragma unroll
        for (int m = 0; m < 4; ++m)
            #pragma unroll
            for (int q = 0; q < 4; ++q) vmin[m][q] = 1e30f;

        #pragma unroll
        for (int n = 0; n < 4; ++n) {
            const int cg = colBase + wid * 64 + n * 16 + frow;
            #pragma unroll
            for (int m = 0; m < 4; ++m) {
                us4 pk;
                #pragma unroll
                for (int q = 0; q < 4; ++q) {
                    const float raw = fmaxf(0.5f * (1.0f - acc[m][n][q]), 0.0f);
                    vmin[m][q] = fminf(vmin[m][q], raw);
                    pk[q] = f2bfbits(raw);
                }
                *reinterpret_cast<us4*>(Q + (size_t)cg * S + rowBase + m * 16 + kgrp * 4) = pk;
            }
        }
        #pragma unroll
        for (int m = 0; m < 4; ++m)
            #pragma unroll
            for (int q = 0; q < 4; ++q) {
                float v = vmin[m][q];
                v = fminf(v, __shfl_xor(v, 1, 64));
                v = fminf(v, __shfl_xor(v, 2, 64));
                v = fminf(v, __shfl_xor(v, 4, 64));
                v = fminf(v, __shfl_xor(v, 8, 64));
                if (frow == 0)
                    atomicMin((unsigned int*)&rowmin[rowBase + m * 16 + kgrp * 4 + q],
                              __float_as_uint(v));
            }
    }
}

// ---------------- rowsum over s-chunks (exp2 form, 4 ops/elem) ------------
// grid = 144 r-strips x 8 s-chunks = 1152 blocks; block: 64 r x 1152 s.
__global__ __launch_bounds__(256) void k_rowsum(const __hip_bfloat16* __restrict__ Q,
                                                const float* __restrict__ rowmin,
                                                float* __restrict__ rowsum) {
    __shared__ float sBrN[64];   // -A2C / (rowmin+eps)
    __shared__ float srs[64];
    const int t  = threadIdx.x;
    const int r0 = (blockIdx.x >> 3) * 64;
    const int s0 = (blockIdx.x & 7) * SCH;
    if (t < 64) {
        sBrN[t] = -A2C / (rowmin[r0 + t] + 1e-5f);
        srs[t]  = 0.f;
    }
    __syncthreads();
    const int roct = (t & 7) * 8;
    const int ss   = t >> 3;          // 0..31
    float brn[8];
    #pragma unroll
    for (int j = 0; j < 8; ++j) brn[j] = sBrN[roct + j];
    const __hip_bfloat16* base = Q + r0 + roct;

    float sums[8] = {};
    #pragma unroll 4
    for (int i = 0; i < SCH / 32; ++i) {
        const int s = s0 + ss + i * 32;
        const us8 v = *reinterpret_cast<const us8*>(base + (size_t)s * S);
        #pragma unroll
        for (int j = 0; j < 8; ++j)
            sums[j] += exp2f(fmaf(brn[j], bf2f(v[j]), A2C));
    }
    #pragma unroll
    for (int j = 0; j < 8; ++j) {
        float x = sums[j];
        x += __shfl_xor(x, 8, 64);
        x += __shfl_xor(x, 16, 64);
        x += __shfl_xor(x, 32, 64);
        if ((t & 63) < 8) atomicAdd(&srs[roct + j], x);
    }
    __syncthreads();
    if (t < 64) atomicAdd(&rowsum[r0 + t], srs[t]);
}

// ---------------- colmax in LOG space (3 ops/elem, no exp) ----------------
// colmaxLog[s] = max_r (A2C - log2(rowsum[r]) - (A2C/(rowmin[r]+eps))*raw) + 64
__global__ __launch_bounds__(256) void k_colmax(const __hip_bfloat16* __restrict__ Q,
                                                const float* __restrict__ rowmin,
                                                const float* __restrict__ rowsum,
                                                float* __restrict__ colmaxLog) {
    __shared__ float sBrN[64];
    __shared__ float sCA[64];
    const int t  = threadIdx.x;
    const int r0 = (blockIdx.x >> 3) * 64;
    const int s0 = (blockIdx.x & 7) * SCH;
    if (t < 64) {
        sBrN[t] = -A2C / (rowmin[r0 + t] + 1e-5f);
        sCA[t]  = A2C + 64.0f - __log2f(rowsum[r0 + t]);
    }
    __syncthreads();
    const int roct = (t & 7) * 8;
    const int ss   = t >> 3;
    float brn[8], ca[8];
    #pragma unroll
    for (int j = 0; j < 8; ++j) { brn[j] = sBrN[roct + j]; ca[j] = sCA[roct + j]; }
    const __hip_bfloat16* base = Q + r0 + roct;

    #pragma unroll 4
    for (int i = 0; i < SCH / 32; ++i) {
        const int s = s0 + ss + i * 32;
        const us8 v = *reinterpret_cast<const us8*>(base + (size_t)s * S);
        float mx = -1e30f;
        #pragma unroll
        for (int j = 0; j < 8; ++j)
            mx = fmaxf(mx, fmaf(brn[j], bf2f(v[j]), ca[j]));
        mx = fmaxf(mx, __shfl_xor(mx, 1, 64));
        mx = fmaxf(mx, __shfl_xor(mx, 2, 64));
        mx = fmaxf(mx, __shfl_xor(mx, 4, 64));
        if ((t & 7) == 0) {
            mx = fmaxf(mx, 0.0f);
            if (mx > colmaxLog[s])           // cheap check; atomic re-verifies
                atomicMax((unsigned int*)&colmaxLog[s], __float_as_uint(mx));
        }
    }
}

// ---------------- final: loss = -log(mean_s 2^(cl[s]-64)) ----------------
__global__ __launch_bounds__(256) void k_final(const float* __restrict__ colmaxLog,
                                               float* __restrict__ out) {
    float s = 0.f;
    for (int i = threadIdx.x; i < S; i += 256) s += exp2f(colmaxLog[i]);
    for (int m = 1; m < 64; m <<= 1) s += __shfl_xor(s, m, 64);
    __shared__ float red[4];
    if ((threadIdx.x & 63) == 0) red[threadIdx.x >> 6] = s;
    __syncthreads();
    if (threadIdx.x == 0) {
        const float total = red[0] + red[1] + red[2] + red[3];
        // 2^-64 / S
        out[0] = -logf(total * (5.421010862427522e-20f / (float)S));
    }
}

extern "C" void kernel_launch(void* const* d_in, const int* in_sizes, int n_in,
                              void* d_out, int out_size, void* d_ws, size_t ws_size,
                              hipStream_t stream) {
    const float* img = (const float*)d_in[0];
    const float* gt  = (const float*)d_in[1];

    float* ws        = (float*)d_ws;
    float* meanT     = ws;                  // 256 f
    float* rowmin    = ws + 256;            // S f
    float* rowsum    = rowmin + S;          // S f
    float* colmaxLog = rowsum + S;          // S f
    __hip_bfloat16* A = (__hip_bfloat16*)(colmaxLog + S);
    __hip_bfloat16* B = A + (size_t)S * C;
    __hip_bfloat16* Q = B + (size_t)S * C;   // 170 MB (fits: proven in r4)
    float* ssqP = (float*)Q;                 // [16][S] partials, dead before Q written
    float* out = (float*)d_out;

    k_mean <<<C, 256, 0, stream>>>(gt, meanT);
    k_ssq  <<<288, 256, 0, stream>>>(img, gt, meanT, ssqP);
    k_init <<<(S + 255) / 256, 256, 0, stream>>>(rowmin, rowsum, colmaxLog);
    k_write<<<288, 256, 0, stream>>>(img, gt, meanT, ssqP, A, B);

    k_gemm_store<<<432, 256, 0, stream>>>(A, B, rowmin, Q);
    k_rowsum<<<1152, 256, 0, stream>>>(Q, rowmin, rowsum);
    k_colmax<<<1152, 256, 0, stream>>>(Q, rowmin, rowsum, colmaxLog);

    k_final<<<1, 256, 0, stream>>>(colmaxLog, out);
}

// Round 7
// 247.849 us; speedup vs baseline: 1.4318x; 1.4318x over previous
//
#include <hip/hip_runtime.h>
#include <hip/hip_bf16.h>

#define S 9216      // 96*96 spatial positions
#define C 256       // channels
#define NCT 12      // 256-col tiles per GEMM block
#define NG  (NCT*8) // kt-steps per block (96)
#define SCH 1152    // s-chunk for rowsum/colmax kernels

typedef __bf16 bf16x8 __attribute__((ext_vector_type(8)));
typedef float f32x4 __attribute__((ext_vector_type(4)));
typedef unsigned short us8 __attribute__((ext_vector_type(8)));
typedef unsigned short us4 __attribute__((ext_vector_type(4)));

#define GLOAD_LDS16(g, l) __builtin_amdgcn_global_load_lds( \
    (const __attribute__((address_space(1))) void*)(g),     \
    (__attribute__((address_space(3))) void*)(l), 16, 0, 0)

#define A2C 2.8853900817779268f   // 2*log2(e) = 2/ln2

__device__ __forceinline__ float bf2f(unsigned short u) {
    return __uint_as_float(((unsigned)u) << 16);
}
__device__ __forceinline__ unsigned short f2bfbits(float x) {
    __hip_bfloat16 h = __float2bfloat16(x);
    return *reinterpret_cast<unsigned short*>(&h);
}

// ---------------- mean of gt over spatial, per channel ----------------
__global__ __launch_bounds__(256) void k_mean(const float* __restrict__ gt,
                                              float* __restrict__ meanT) {
    const int c = blockIdx.x;
    const float* p = gt + (size_t)c * S;
    float s = 0.f;
    for (int i = threadIdx.x; i < S; i += 256) s += p[i];
    for (int m = 1; m < 64; m <<= 1) s += __shfl_xor(s, m, 64);
    __shared__ float red[4];
    if ((threadIdx.x & 63) == 0) red[threadIdx.x >> 6] = s;
    __syncthreads();
    if (threadIdx.x == 0)
        meanT[c] = (red[0] + red[1] + red[2] + red[3]) * (1.0f / S);
}

// ---------------- partial centered sum-of-squares over 32-channel parts ----
__global__ __launch_bounds__(256) void k_ssq(const float* __restrict__ img,
                                             const float* __restrict__ gt,
                                             const float* __restrict__ meanT,
                                             float* __restrict__ ssqP) {  // [16][S]
    __shared__ float sm[32];
    const int part = blockIdx.x & 7;
    const int sb   = blockIdx.x >> 3;
    const int t    = threadIdx.x;
    if (t < 32) sm[t] = meanT[part * 32 + t];
    __syncthreads();
    const int s = sb * 256 + t;
    float si = 0.f, st = 0.f;
    #pragma unroll 8
    for (int k = 0; k < 32; ++k) {
        const int c = part * 32 + k;
        const float m  = sm[k];
        const float di = img[(size_t)c * S + s] - m;
        const float dt = gt [(size_t)c * S + s] - m;
        si += di * di;
        st += dt * dt;
    }
    ssqP[(size_t)part * S + s]       = si;
    ssqP[(size_t)(part + 8) * S + s] = st;
}

// ---------------- write normalized bf16 A,B (transposed to [S][C]) --------
__global__ __launch_bounds__(256) void k_write(const float* __restrict__ img,
                                               const float* __restrict__ gt,
                                               const float* __restrict__ meanT,
                                               const float* __restrict__ ssqP,
                                               __hip_bfloat16* __restrict__ A,
                                               __hip_bfloat16* __restrict__ B) {
    __shared__ float sm[32];
    const int part = blockIdx.x & 7;
    const int sb   = blockIdx.x >> 3;
    const int t    = threadIdx.x;
    if (t < 32) sm[t] = meanT[part * 32 + t];
    __syncthreads();
    const int s = sb * 256 + t;
    float si = 0.f, st = 0.f;
    #pragma unroll
    for (int p = 0; p < 8; ++p) {
        si += ssqP[(size_t)p * S + s];
        st += ssqP[(size_t)(p + 8) * S + s];
    }
    const float ri = 1.0f / fmaxf(sqrtf(si), 1e-12f);
    const float rt = 1.0f / fmaxf(sqrtf(st), 1e-12f);
    const int c0 = part * 32;
    #pragma unroll
    for (int cc = 0; cc < 4; ++cc) {
        us8 va, vb;
        #pragma unroll
        for (int e = 0; e < 8; ++e) {
            const int c = c0 + cc * 8 + e;
            const float m = sm[cc * 8 + e];
            va[e] = f2bfbits((img[(size_t)c * S + s] - m) * ri);
            vb[e] = f2bfbits((gt [(size_t)c * S + s] - m) * rt);
        }
        *reinterpret_cast<us8*>(A + (size_t)s * C + c0 + cc * 8) = va;
        *reinterpret_cast<us8*>(B + (size_t)s * C + c0 + cc * 8) = vb;
    }
}

// ---------------- init reduction buffers ----------------
__global__ __launch_bounds__(256) void k_init(float* __restrict__ rowmin,
                                              float* __restrict__ rowsum,
                                              float* __restrict__ colmaxLog) {
    const int i = blockIdx.x * 256 + threadIdx.x;
    if (i < S) {
        rowmin[i]     = __uint_as_float(0x7f800000u);  // +inf
        rowsum[i]     = 0.f;
        colmaxLog[i]  = 0.f;   // biased log2 max; 0 == 2^-64 ~ 0
    }
}

// ---------------- GEMM pass: store raw^T + rowmin ----------------
// 64-row A panel (full K=256 resident, 32KB) + 256-col B stages (2x16KB).
// LDS = 64KB -> 2 blocks/CU. Wave tile 64x64. Counted vmcnt(4).
__global__ __launch_bounds__(256, 2) void k_gemm_store(const __hip_bfloat16* __restrict__ A,
                                                       const __hip_bfloat16* __restrict__ B,
                                                       float* __restrict__ rowmin,
                                                       __hip_bfloat16* __restrict__ Q) {
    __shared__ alignas(16) __hip_bfloat16 As[64 * 256];       // 32 KB
    __shared__ alignas(16) __hip_bfloat16 Bs[2 * 256 * 32];   // 32 KB
    const int tid  = threadIdx.x;
    const int lane = tid & 63;
    const int wid  = tid >> 6;       // wave owns 64-col strip wid*64
    // XCD-aware bijective swizzle: 432 = 8 * 54
    const int orig = blockIdx.x;
    const int wg   = (orig & 7) * 54 + (orig >> 3);
    const int rowBase = (wg / 3) * 64;
    const int cb0     = (wg % 3) * 3072;

    const int frow = lane & 15;
    const int kgrp = lane >> 4;

    // ---- stage A (full K, 8 loads/thread)
    {
        const int arow_lo = lane >> 5;
        const int achunk  = lane & 31;
        #pragma unroll
        for (int j = 0; j < 8; ++j) {
            const int row = wid * 16 + j * 2 + arow_lo;
            const int cc  = achunk ^ (row & 7);
            GLOAD_LDS16(A + (size_t)(rowBase + row) * C + cc * 8,
                        &As[(wid * 16 + j * 2) * 256 + lane * 8]);
        }
    }
    // ---- B prologue: stages g=0,1 (4 loads/thread each)
    const int bcol_lo = lane >> 2;
    const int bchunk  = (lane & 3) ^ ((lane >> 3) & 3);
    #pragma unroll
    for (int g = 0; g < 2; ++g) {
        const int cb = cb0 + (g >> 3) * 256;
        const int kt = g & 7;
        #pragma unroll
        for (int i = 0; i < 4; ++i) {
            const int col = wid * 16 + i * 64 + bcol_lo;
            GLOAD_LDS16(B + (size_t)(cb + col) * C + kt * 32 + bchunk * 8,
                        &Bs[(g & 1) * 8192 + wid * 512 + i * 2048 + lane * 8]);
        }
    }

    const int bswz = (kgrp ^ ((frow >> 1) & 3)) * 8;

    for (int t = 0; t < NCT; ++t) {
        f32x4 acc[4][4] = {};
        #pragma unroll
        for (int kt = 0; kt < 8; ++kt) {
            const int g = t * 8 + kt;
            if (g < NG - 1) asm volatile("s_waitcnt vmcnt(4)" ::: "memory");
            else            asm volatile("s_waitcnt vmcnt(0)" ::: "memory");
            __builtin_amdgcn_s_barrier();

            bf16x8 af[4], bfr[4];
            #pragma unroll
            for (int m = 0; m < 4; ++m) {
                const int row = m * 16 + frow;
                const int p   = (kt * 4 + kgrp) ^ (frow & 7);
                af[m] = *reinterpret_cast<const bf16x8*>(&As[row * 256 + p * 8]);
            }
            const int bbase = (g & 1) * 8192;
            #pragma unroll
            for (int n = 0; n < 4; ++n) {
                const int col = wid * 64 + n * 16 + frow;
                bfr[n] = *reinterpret_cast<const bf16x8*>(&Bs[bbase + col * 32 + bswz]);
            }
            #pragma unroll
            for (int m = 0; m < 4; ++m)
                #pragma unroll
                for (int n = 0; n < 4; ++n)
                    acc[m][n] = __builtin_amdgcn_mfma_f32_16x16x32_bf16(af[m], bfr[n], acc[m][n], 0, 0, 0);

            __builtin_amdgcn_s_barrier();

            if (g + 2 < NG) {
                const int g2 = g + 2;
                const int cb = cb0 + (g2 >> 3) * 256;
                const int k2 = g2 & 7;
                #pragma unroll
                for (int i = 0; i < 4; ++i) {
                    const int col = wid * 16 + i * 64 + bcol_lo;
                    GLOAD_LDS16(B + (size_t)(cb + col) * C + k2 * 32 + bchunk * 8,
                                &Bs[(g2 & 1) * 8192 + wid * 512 + i * 2048 + lane * 8]);
                }
            }
        }

        // ---- epilogue tile t
        const int colBase = cb0 + t * 256;
        float vmin[4][4];
        #pragma unroll
        for (int m = 0; m < 4; ++m)
            #pragma unroll
            for (int q = 0; q < 4; ++q) vmin[m][q] = 1e30f;

        #pragma unroll
        for (int n = 0; n < 4; ++n) {
            const int cg = colBase + wid * 64 + n * 16 + frow;
            #pragma unroll
            for (int m = 0; m < 4; ++m) {
                us4 pk;
                #pragma unroll
                for (int q = 0; q < 4; ++q) {
                    const float raw = fmaxf(0.5f * (1.0f - acc[m][n][q]), 0.0f);
                    vmin[m][q] = fminf(vmin[m][q], raw);
                    pk[q] = f2bfbits(raw);
                }
                *reinterpret_cast<us4*>(Q + (size_t)cg * S + rowBase + m * 16 + kgrp * 4) = pk;
            }
        }
        #pragma unroll
        for (int m = 0; m < 4; ++m)
            #pragma unroll
            for (int q = 0; q < 4; ++q) {
                float v = vmin[m][q];
                v = fminf(v, __shfl_xor(v, 1, 64));
                v = fminf(v, __shfl_xor(v, 2, 64));
                v = fminf(v, __shfl_xor(v, 4, 64));
                v = fminf(v, __shfl_xor(v, 8, 64));
                if (frow == 0)
                    atomicMin((unsigned int*)&rowmin[rowBase + m * 16 + kgrp * 4 + q],
                              __float_as_uint(v));
            }
    }
}

// ---------------- rowsum over s-chunks (exp2 form) ------------
__global__ __launch_bounds__(256) void k_rowsum(const __hip_bfloat16* __restrict__ Q,
                                                const float* __restrict__ rowmin,
                                                float* __restrict__ rowsum) {
    __shared__ float sBrN[64];   // -A2C / (rowmin+eps)
    __shared__ float srs[64];
    const int t  = threadIdx.x;
    const int r0 = (blockIdx.x >> 3) * 64;
    const int s0 = (blockIdx.x & 7) * SCH;
    if (t < 64) {
        sBrN[t] = -A2C / (rowmin[r0 + t] + 1e-5f);
        srs[t]  = 0.f;
    }
    __syncthreads();
    const int roct = (t & 7) * 8;
    const int ss   = t >> 3;          // 0..31
    float brn[8];
    #pragma unroll
    for (int j = 0; j < 8; ++j) brn[j] = sBrN[roct + j];
    const __hip_bfloat16* base = Q + r0 + roct;

    float sums[8] = {};
    #pragma unroll 4
    for (int i = 0; i < SCH / 32; ++i) {
        const int s = s0 + ss + i * 32;
        const us8 v = *reinterpret_cast<const us8*>(base + (size_t)s * S);
        #pragma unroll
        for (int j = 0; j < 8; ++j)
            sums[j] += exp2f(fmaf(brn[j], bf2f(v[j]), A2C));
    }
    #pragma unroll
    for (int j = 0; j < 8; ++j) {
        float x = sums[j];
        x += __shfl_xor(x, 8, 64);
        x += __shfl_xor(x, 16, 64);
        x += __shfl_xor(x, 32, 64);
        if ((t & 63) < 8) atomicAdd(&srs[roct + j], x);
    }
    __syncthreads();
    if (t < 64) atomicAdd(&rowsum[r0 + t], srs[t]);
}

// ---------------- colmax in LOG space (3 ops/elem, no exp) ----------------
// colmaxLog[s] = max_r (A2C + 64 - log2(rowsum[r]) - (A2C/(rowmin[r]+eps))*raw)
// Unconditional fire-and-forget atomicMax (r6's check-before-atomic made the
// loop latency-bound on a contended cross-XCD line: 180us @ 4% VALU).
__global__ __launch_bounds__(256) void k_colmax(const __hip_bfloat16* __restrict__ Q,
                                                const float* __restrict__ rowmin,
                                                const float* __restrict__ rowsum,
                                                float* __restrict__ colmaxLog) {
    __shared__ float sBrN[64];
    __shared__ float sCA[64];
    const int t  = threadIdx.x;
    const int r0 = (blockIdx.x >> 3) * 64;
    const int s0 = (blockIdx.x & 7) * SCH;
    if (t < 64) {
        sBrN[t] = -A2C / (rowmin[r0 + t] + 1e-5f);
        sCA[t]  = A2C + 64.0f - __log2f(rowsum[r0 + t]);
    }
    __syncthreads();
    const int roct = (t & 7) * 8;
    const int ss   = t >> 3;
    float brn[8], ca[8];
    #pragma unroll
    for (int j = 0; j < 8; ++j) { brn[j] = sBrN[roct + j]; ca[j] = sCA[roct + j]; }
    const __hip_bfloat16* base = Q + r0 + roct;

    #pragma unroll 4
    for (int i = 0; i < SCH / 32; ++i) {
        const int s = s0 + ss + i * 32;
        const us8 v = *reinterpret_cast<const us8*>(base + (size_t)s * S);
        float mx = -1e30f;
        #pragma unroll
        for (int j = 0; j < 8; ++j)
            mx = fmaxf(mx, fmaf(brn[j], bf2f(v[j]), ca[j]));
        mx = fmaxf(mx, __shfl_xor(mx, 1, 64));
        mx = fmaxf(mx, __shfl_xor(mx, 2, 64));
        mx = fmaxf(mx, __shfl_xor(mx, 4, 64));
        if ((t & 7) == 0)
            atomicMax((unsigned int*)&colmaxLog[s], __float_as_uint(fmaxf(mx, 0.0f)));
    }
}

// ---------------- final: loss = -log(mean_s 2^(cl[s]-64)) ----------------
__global__ __launch_bounds__(256) void k_final(const float* __restrict__ colmaxLog,
                                               float* __restrict__ out) {
    float s = 0.f;
    for (int i = threadIdx.x; i < S; i += 256) s += exp2f(colmaxLog[i]);
    for (int m = 1; m < 64; m <<= 1) s += __shfl_xor(s, m, 64);
    __shared__ float red[4];
    if ((threadIdx.x & 63) == 0) red[threadIdx.x >> 6] = s;
    __syncthreads();
    if (threadIdx.x == 0) {
        const float total = red[0] + red[1] + red[2] + red[3];
        // 2^-64 / S
        out[0] = -logf(total * (5.421010862427522e-20f / (float)S));
    }
}

extern "C" void kernel_launch(void* const* d_in, const int* in_sizes, int n_in,
                              void* d_out, int out_size, void* d_ws, size_t ws_size,
                              hipStream_t stream) {
    const float* img = (const float*)d_in[0];
    const float* gt  = (const float*)d_in[1];

    float* ws        = (float*)d_ws;
    float* meanT     = ws;                  // 256 f
    float* rowmin    = ws + 256;            // S f
    float* rowsum    = rowmin + S;          // S f
    float* colmaxLog = rowsum + S;          // S f
    __hip_bfloat16* A = (__hip_bfloat16*)(colmaxLog + S);
    __hip_bfloat16* B = A + (size_t)S * C;
    __hip_bfloat16* Q = B + (size_t)S * C;   // 170 MB (fits: proven in r4)
    float* ssqP = (float*)Q;                 // [16][S] partials, dead before Q written
    float* out = (float*)d_out;

    k_mean <<<C, 256, 0, stream>>>(gt, meanT);
    k_ssq  <<<288, 256, 0, stream>>>(img, gt, meanT, ssqP);
    k_init <<<(S + 255) / 256, 256, 0, stream>>>(rowmin, rowsum, colmaxLog);
    k_write<<<288, 256, 0, stream>>>(img, gt, meanT, ssqP, A, B);

    k_gemm_store<<<432, 256, 0, stream>>>(A, B, rowmin, Q);
    k_rowsum<<<1152, 256, 0, stream>>>(Q, rowmin, rowsum);
    k_colmax<<<1152, 256, 0, stream>>>(Q, rowmin, rowsum, colmaxLog);

    k_final<<<1, 256, 0, stream>>>(colmaxLog, out);
}